// Round 4
// baseline (925.313 us; speedup 1.0000x reference)
//
#include <hip/hip_runtime.h>
#include <stdint.h>

// ---------------------------------------------------------------------------
// LIF layer, T=200 sequential steps over B*N = 262144 neurons.
// Bit-exact replication of the JAX reference (verified: zero spike flips over
// 52.4M Bernoulli draws; absmax 2^-7 is comparison quantization, not math).
// All float arithmetic must stay byte-identical:
//   - threefry2x32, partitionable mode
//   - uniform:  bitcast((bits>>9)|0x3f800000) - 1.0f
//   - normal:   sqrt(2) * erfinv(u * 2.0f + nextafter(-1,0))  (XLA Giles poly)
//   - sigmoid:  1 / (1 + exp(-x)),  exp/log1p = OCML
//   - NO fma contraction anywhere
//
// Round 4: SPLIT KERNELS. The scan is occupancy-capped at 4 waves/SIMD
// (B*N = 4096 waves); ~80% of per-step instructions (2x threefry, erfinv,
// log1p) are state-independent. Move them to gen_kernel at T*B*N parallelism
// (8 waves/SIMD), staging noise/us through the d_out regions (each address is
// read-then-overwritten only by the unique thread owning that element — no
// cross-thread hazard). scan_kernel becomes lean and memory-bound, with
// depth-2 register prefetch.
// ---------------------------------------------------------------------------

#define TSTEPS 200
#define BN     262144u            // 64 * 4096
#define TBN    ((size_t)TSTEPS * (size_t)BN)

// ---- threefry2x32, exactly JAX's 20-round schedule; keys wave-uniform ----
__device__ __forceinline__ void tf2x32(uint32_t k0, uint32_t k1,
                                       uint32_t c0, uint32_t c1,
                                       uint32_t& o0, uint32_t& o1) {
  uint32_t ks2 = k0 ^ k1 ^ 0x1BD11BDAu;
  uint32_t x0 = c0 + k0, x1 = c1 + k1;
#define R1(r) { x0 += x1; x1 = (x1 << (r)) | (x1 >> (32 - (r))); x1 ^= x0; }
#define R4A R1(13) R1(15) R1(26) R1(6)
#define R4B R1(17) R1(29) R1(16) R1(24)
  R4A; x0 += k1;  x1 += ks2 + 1u;
  R4B; x0 += ks2; x1 += k0 + 2u;
  R4A; x0 += k0;  x1 += k1 + 3u;
  R4B; x0 += k1;  x1 += ks2 + 4u;
  R4A; x0 += ks2; x1 += k0 + 5u;
#undef R4A
#undef R4B
#undef R1
  o0 = x0; o1 = x1;
}

// ---- XLA erfinv (Giles polynomial), f32, no contraction ----
__device__ __forceinline__ float erfinv_f32(float x) {
#pragma clang fp contract(off)
  float w = -log1pf(-(x * x));
  float p;
  if (w < 5.0f) {
    w = w - 2.5f;
    p =  2.81022636e-08f;
    p =  3.43273939e-07f + p * w;
    p = -3.5233877e-06f  + p * w;
    p = -4.39150654e-06f + p * w;
    p =  0.00021858087f  + p * w;
    p = -0.00125372503f  + p * w;
    p = -0.00417768164f  + p * w;
    p =  0.246640727f    + p * w;
    p =  1.50140941f     + p * w;
  } else {
    w = sqrtf(w) - 3.0f;
    p = -0.000200214257f;
    p =  0.000100950558f + p * w;
    p =  0.00134934322f  + p * w;
    p = -0.00367342844f  + p * w;
    p =  0.00573950773f  + p * w;
    p = -0.0076224613f   + p * w;
    p =  0.00943887047f  + p * w;
    p =  1.00167406f     + p * w;
    p =  2.83297682f     + p * w;
  }
  return p * x;
}

__device__ __forceinline__ float u01(uint32_t b) {
#pragma clang fp contract(off)
  return __uint_as_float((b >> 9) | 0x3f800000u) - 1.0f;
}

// ---- per-step key derivation: keys = split(key(42), 200); kn,ks = split ----
__global__ void keys_kernel(uint4* __restrict__ gK) {
  int t = blockIdx.x * blockDim.x + threadIdx.x;
  if (t >= TSTEPS) return;
  uint32_t K0, K1; tf2x32(0u, 42u, 0u, (uint32_t)t, K0, K1);
  uint32_t n0, n1; tf2x32(K0, K1, 0u, 0u, n0, n1);   // k_noise
  uint32_t s0, s1; tf2x32(K0, K1, 0u, 1u, s0, s1);   // k_spike
  gK[t] = make_uint4(n0, n1, s0, s1);
}

// ---- kernel A: all (t,e)-only randoms at full parallelism ----
// noise(t,e) -> gOut[t*BN+e]          (spike region, consumed by scan)
// us(t,e)    -> gOut[TBN + t*BN+e]    (voltage region, consumed by scan)
__global__ __launch_bounds__(256) void gen_kernel(
    const uint4* __restrict__ gK, float* __restrict__ gOut)
{
#pragma clang fp contract(off)
  const uint32_t t = blockIdx.y;
  const uint32_t e = blockIdx.x * 256u + threadIdx.x;

  uint4 kk = gK[t];
  uint32_t k0 = __builtin_amdgcn_readfirstlane(kk.x);
  uint32_t k1 = __builtin_amdgcn_readfirstlane(kk.y);
  uint32_t k2 = __builtin_amdgcn_readfirstlane(kk.z);
  uint32_t k3 = __builtin_amdgcn_readfirstlane(kk.w);

  const float LO = -0x1.fffffep-1f;          // nextafter(-1, 0)
  const float SQRT2 = 1.4142135623730951f;

  // noise = normal(k_noise) * 0.1
  uint32_t b0, b1; tf2x32(k0, k1, 0u, e, b0, b1);
  float un = u01(b0 ^ b1);
  float x = un * 2.0f + LO;
  x = fmaxf(LO, x);
  float noise = (SQRT2 * erfinv_f32(x)) * 0.1f;

  // spike uniform
  uint32_t c0, c1; tf2x32(k2, k3, 0u, e, c0, c1);
  float us = fmaxf(0.0f, u01(c0 ^ c1));

  size_t off = (size_t)t * BN + e;
  gOut[off] = noise;          // plain (cacheable) store: L3 retains for scan
  gOut[TBN + off] = us;
}

// ---- kernel B: lean sequential scan, memory-bound, depth-2 prefetch ----
__global__ __launch_bounds__(256) void scan_kernel(
    const float* __restrict__ gI,
    const float* __restrict__ gV0, const float* __restrict__ gT0,
    const float* __restrict__ gA0, const float* __restrict__ gS0,
    const float* __restrict__ gN0,
    float* gOut)
{
#pragma clang fp contract(off)
  const uint32_t e = blockIdx.x * 256u + threadIdx.x;

  float V  = gV0[e];
  float Th = gT0[e];
  float Ad = gA0[e];
  float Sy = gS0[e];
  float Nm = gN0[e];

  const float* Ip = gI + e;
  float* Op = gOut + e;          // reads noise(t,e), then writes sf(t,e)
  float* Up = gOut + TBN + e;    // reads us(t,e),    then writes V(t,e)

  // prefetch t=0,1
  float I0 = Ip[0],          N0 = Op[0],          U0 = Up[0];
  float I1 = Ip[(size_t)BN], N1 = Op[(size_t)BN], U1 = Up[(size_t)BN];

  for (int t = 0; t < TSTEPS; ++t) {
    float I2 = 0.0f, N2 = 0.0f, U2 = 0.0f;
    if (t + 2 < TSTEPS) {
      size_t pf = (size_t)(t + 2) * BN;
      I2 = Ip[pf]; N2 = Op[pf]; U2 = Up[pf];
    }

    // serial state update (bit-identical dataflow to the fused kernel)
    float Ieff = (I0 * Sy + Nm) - Ad;
    V = (V + (Ieff - V) * 0.05f) + N0;
    float md = Th - V;                       // == -(V - Th)
    float ex = expf(md);
    float p = 1.0f / (1.0f + ex);
    bool spk = U0 < p;
    float sf = spk ? 1.0f : 0.0f;

    V = spk ? 0.0f : V;
    float thn = Th - 0.1f * (Th - 1.0f);
    Th = spk ? (Th + 0.1f) : thn;
    Th = fminf(fmaxf(Th, 0.5f), 2.0f);
    Ad = Ad * 0.9f + 0.5f * sf;
    Sy = Sy * (1.0f - 0.1f * sf) + 0.05f * (1.0f - Sy);

    size_t so = (size_t)t * BN;
    __builtin_nontemporal_store(sf, Op + so);
    __builtin_nontemporal_store(V,  Up + so);

    I0 = I1; N0 = N1; U0 = U1;
    I1 = I2; N1 = N2; U1 = U2;
  }
}

extern "C" void kernel_launch(void* const* d_in, const int* in_sizes, int n_in,
                              void* d_out, int out_size, void* d_ws, size_t ws_size,
                              hipStream_t stream) {
  const float* I    = (const float*)d_in[0];
  const float* V0   = (const float*)d_in[1];
  const float* Vth0 = (const float*)d_in[2];
  const float* ad0  = (const float*)d_in[3];
  const float* sy0  = (const float*)d_in[4];
  const float* nm0  = (const float*)d_in[5];
  float* out = (float*)d_out;
  uint4* ktab = (uint4*)d_ws;   // 200 * 16 B = 3.2 KB of workspace

  keys_kernel<<<1, 256, 0, stream>>>(ktab);
  gen_kernel<<<dim3(BN / 256, TSTEPS), 256, 0, stream>>>(ktab, out);
  scan_kernel<<<BN / 256, 256, 0, stream>>>(I, V0, Vth0, ad0, sy0, nm0, out);
}

// Round 5
// 856.904 us; speedup vs baseline: 1.0798x; 1.0798x over previous
//
#include <hip/hip_runtime.h>
#include <stdint.h>

// ---------------------------------------------------------------------------
// LIF layer, T=200 sequential steps over B*N = 262144 neurons.
// Bit-exact replication of the JAX reference (verified: zero spike flips over
// 52.4M Bernoulli draws). All float arithmetic stays byte-identical:
//   - threefry2x32, partitionable mode
//   - uniform:  bitcast((bits>>9)|0x3f800000) - 1.0f
//   - normal:   sqrt(2) * erfinv(u * 2.0f + nextafter(-1,0))  (XLA Giles poly)
//   - sigmoid:  1 / (1 + exp(-x)),  exp/log1p = OCML, IEEE divide
//   - NO fma contraction anywhere
//
// Round 5: FUSED again (split round-4 measured slower: gen 331 + scan ~235 >
// fused 489), now with 2 ELEMENTS PER THREAD. Round 3 showed the compiler
// un-does cross-iteration pipelining; but it DOES interleave independent
// intra-iteration chains. Two elements/thread doubles in-block ILP (2x
// threefry pairs, 2x erfinv, 2x exp/div, all independent) to fill the
// dependence-latency bubbles that left the 4-wave/SIMD fused kernel at ~50%
// true VALU busy. Streams e and e+131072 keep all loads/stores coalesced.
// Depth-2 register prefetch on I covers HBM latency.
// ---------------------------------------------------------------------------

#define TSTEPS 200
#define BN     262144u            // 64 * 4096
#define HALF   131072u            // BN / 2
#define TBN    ((size_t)TSTEPS * (size_t)BN)

// ---- threefry2x32, exactly JAX's 20-round schedule; keys wave-uniform ----
__device__ __forceinline__ void tf2x32(uint32_t k0, uint32_t k1,
                                       uint32_t c0, uint32_t c1,
                                       uint32_t& o0, uint32_t& o1) {
  uint32_t ks2 = k0 ^ k1 ^ 0x1BD11BDAu;
  uint32_t x0 = c0 + k0, x1 = c1 + k1;
#define R1(r) { x0 += x1; x1 = (x1 << (r)) | (x1 >> (32 - (r))); x1 ^= x0; }
#define R4A R1(13) R1(15) R1(26) R1(6)
#define R4B R1(17) R1(29) R1(16) R1(24)
  R4A; x0 += k1;  x1 += ks2 + 1u;
  R4B; x0 += ks2; x1 += k0 + 2u;
  R4A; x0 += k0;  x1 += k1 + 3u;
  R4B; x0 += k1;  x1 += ks2 + 4u;
  R4A; x0 += ks2; x1 += k0 + 5u;
#undef R4A
#undef R4B
#undef R1
  o0 = x0; o1 = x1;
}

// ---- XLA erfinv (Giles polynomial), f32, no contraction ----
__device__ __forceinline__ float erfinv_f32(float x) {
#pragma clang fp contract(off)
  float w = -log1pf(-(x * x));
  float p;
  if (w < 5.0f) {
    w = w - 2.5f;
    p =  2.81022636e-08f;
    p =  3.43273939e-07f + p * w;
    p = -3.5233877e-06f  + p * w;
    p = -4.39150654e-06f + p * w;
    p =  0.00021858087f  + p * w;
    p = -0.00125372503f  + p * w;
    p = -0.00417768164f  + p * w;
    p =  0.246640727f    + p * w;
    p =  1.50140941f     + p * w;
  } else {
    w = sqrtf(w) - 3.0f;
    p = -0.000200214257f;
    p =  0.000100950558f + p * w;
    p =  0.00134934322f  + p * w;
    p = -0.00367342844f  + p * w;
    p =  0.00573950773f  + p * w;
    p = -0.0076224613f   + p * w;
    p =  0.00943887047f  + p * w;
    p =  1.00167406f     + p * w;
    p =  2.83297682f     + p * w;
  }
  return p * x;
}

__device__ __forceinline__ float u01(uint32_t b) {
#pragma clang fp contract(off)
  return __uint_as_float((b >> 9) | 0x3f800000u) - 1.0f;
}

__device__ __forceinline__ float noise_from(uint32_t k0, uint32_t k1, uint32_t e) {
#pragma clang fp contract(off)
  const float LO = -0x1.fffffep-1f;          // nextafter(-1, 0)
  const float SQRT2 = 1.4142135623730951f;
  uint32_t b0, b1; tf2x32(k0, k1, 0u, e, b0, b1);
  float un = u01(b0 ^ b1);
  float x = un * 2.0f + LO;
  x = fmaxf(LO, x);
  return (SQRT2 * erfinv_f32(x)) * 0.1f;
}

__device__ __forceinline__ float us_from(uint32_t k0, uint32_t k1, uint32_t e) {
#pragma clang fp contract(off)
  uint32_t c0, c1; tf2x32(k0, k1, 0u, e, c0, c1);
  return fmaxf(0.0f, u01(c0 ^ c1));
}

// one element's serial state update; byte-identical to the verified dataflow
struct LifState { float V, Th, Ad, Sy, Nm; };
__device__ __forceinline__ void step_update(LifState& s, float I, float noise,
                                            float us, float& sf_out, float& V_out) {
#pragma clang fp contract(off)
  float Ieff = (I * s.Sy + s.Nm) - s.Ad;
  float V = (s.V + (Ieff - s.V) * 0.05f) + noise;
  float md = s.Th - V;                     // == -(V - Th)
  float ex = expf(md);
  float p = 1.0f / (1.0f + ex);
  bool spk = us < p;
  float sf = spk ? 1.0f : 0.0f;
  V = spk ? 0.0f : V;
  float thn = s.Th - 0.1f * (s.Th - 1.0f);
  float Th = spk ? (s.Th + 0.1f) : thn;
  s.Th = fminf(fmaxf(Th, 0.5f), 2.0f);
  s.Ad = s.Ad * 0.9f + 0.5f * sf;
  s.Sy = s.Sy * (1.0f - 0.1f * sf) + 0.05f * (1.0f - s.Sy);
  s.V = V;
  sf_out = sf; V_out = V;
}

// ---- per-step key derivation: keys = split(key(42), 200); kn,ks = split ----
__global__ void keys_kernel(uint4* __restrict__ gK) {
  int t = blockIdx.x * blockDim.x + threadIdx.x;
  if (t >= TSTEPS) return;
  uint32_t K0, K1; tf2x32(0u, 42u, 0u, (uint32_t)t, K0, K1);
  uint32_t n0, n1; tf2x32(K0, K1, 0u, 0u, n0, n1);   // k_noise
  uint32_t s0, s1; tf2x32(K0, K1, 0u, 1u, s0, s1);   // k_spike
  gK[t] = make_uint4(n0, n1, s0, s1);
}

__global__ __launch_bounds__(256) void lif2_kernel(
    const float* __restrict__ gI,
    const float* __restrict__ gV0, const float* __restrict__ gT0,
    const float* __restrict__ gA0, const float* __restrict__ gS0,
    const float* __restrict__ gN0,
    const uint4* __restrict__ gK,
    float* __restrict__ gOut)
{
#pragma clang fp contract(off)
  const uint32_t e0 = blockIdx.x * 256u + threadIdx.x;   // [0, HALF)
  const uint32_t e1 = e0 + HALF;                          // [HALF, BN)

  LifState A = { gV0[e0], gT0[e0], gA0[e0], gS0[e0], gN0[e0] };
  LifState Bs = { gV0[e1], gT0[e1], gA0[e1], gS0[e1], gN0[e1] };

  const float* Ipa = gI + e0;
  const float* Ipb = gI + e1;
  float* Soa = gOut + e0;            // spikes as 0.0/1.0 float
  float* Sob = gOut + e1;
  float* Voa = gOut + TBN + e0;      // voltages
  float* Vob = gOut + TBN + e1;

  // depth-2 prefetch of the input current
  float I0a = Ipa[0],          I0b = Ipb[0];
  float I1a = Ipa[(size_t)BN], I1b = Ipb[(size_t)BN];

  for (int t = 0; t < TSTEPS; ++t) {
    // issue t+2 loads first (wave-uniform guard, 2 SALU)
    float I2a = 0.0f, I2b = 0.0f;
    if (t + 2 < TSTEPS) {
      size_t pf = (size_t)(t + 2) * BN;
      I2a = Ipa[pf]; I2b = Ipb[pf];
    }

    uint4 kk = gK[t];
    uint32_t k0 = __builtin_amdgcn_readfirstlane(kk.x);
    uint32_t k1 = __builtin_amdgcn_readfirstlane(kk.y);
    uint32_t k2 = __builtin_amdgcn_readfirstlane(kk.z);
    uint32_t k3 = __builtin_amdgcn_readfirstlane(kk.w);

    // two fully independent RNG + state chains — the scheduler interleaves
    float na = noise_from(k0, k1, e0);
    float nb = noise_from(k0, k1, e1);
    float ua = us_from(k2, k3, e0);
    float ub = us_from(k2, k3, e1);

    float sfa, Va, sfb, Vb;
    step_update(A,  I0a, na, ua, sfa, Va);
    step_update(Bs, I0b, nb, ub, sfb, Vb);

    size_t so = (size_t)t * BN;
    __builtin_nontemporal_store(sfa, Soa + so);
    __builtin_nontemporal_store(sfb, Sob + so);
    __builtin_nontemporal_store(Va,  Voa + so);
    __builtin_nontemporal_store(Vb,  Vob + so);

    I0a = I1a; I0b = I1b;
    I1a = I2a; I1b = I2b;
  }
}

extern "C" void kernel_launch(void* const* d_in, const int* in_sizes, int n_in,
                              void* d_out, int out_size, void* d_ws, size_t ws_size,
                              hipStream_t stream) {
  const float* I    = (const float*)d_in[0];
  const float* V0   = (const float*)d_in[1];
  const float* Vth0 = (const float*)d_in[2];
  const float* ad0  = (const float*)d_in[3];
  const float* sy0  = (const float*)d_in[4];
  const float* nm0  = (const float*)d_in[5];
  float* out = (float*)d_out;
  uint4* ktab = (uint4*)d_ws;   // 200 * 16 B = 3.2 KB of workspace

  keys_kernel<<<1, 256, 0, stream>>>(ktab);
  lif2_kernel<<<HALF / 256, 256, 0, stream>>>(I, V0, Vth0, ad0, sy0, nm0, ktab, out);
}